// Round 15
// baseline (376.063 us; speedup 1.0000x reference)
//
#include <hip/hip_runtime.h>

#define NN 100000
#define NNZV 1600000
#define EE 1000000
#define NB 782              // row buckets of 128 rows
#define CHK 4096            // entries per sort chunk
#define NCH 391             // chunks per matrix (391*4096 >= 1.6M)
#define PADB 2048           // max per-bucket padding (128 rows x 16)

typedef __attribute__((ext_vector_type(4))) float f32x4;
typedef __attribute__((ext_vector_type(8))) short bf16x8;
typedef __attribute__((ext_vector_type(8))) unsigned short us8;

__device__ __forceinline__ unsigned short f2b(float f){
  unsigned int u = __builtin_bit_cast(unsigned int, f);
  u += 0x7FFFu + ((u >> 16) & 1u);
  return (unsigned short)(u >> 16);
}
__device__ __forceinline__ float b2f(unsigned short s){
  unsigned int u = ((unsigned int)s) << 16;
  return __builtin_bit_cast(float, u);
}
__device__ __forceinline__ float ftanh(float x){
  x = fminf(15.f, fmaxf(-15.f, x));
  float e = __expf(2.f * x);
  return (e - 1.f) / (e + 1.f);
}
__device__ __forceinline__ float fsigm(float x){
  x = fminf(30.f, fmaxf(-30.f, x));
  return 1.f / (1.f + __expf(-x));
}

// XOR swizzle in 16B units within a row of RB bytes; returns ushort index.
template<int RB>
__device__ __forceinline__ int swzi(int row, int kbyte){
  constexpr int UM = (RB/16 - 1) < 15 ? (RB/16 - 1) : 15;
  int unit = (kbyte >> 4) ^ (row & UM);
  return (row*RB + (unit << 4) + (kbyte & 15)) >> 1;
}

// ============ bucket-sort build (deterministic) ============

__global__ __launch_bounds__(256) void k_bhist(const int* __restrict__ rowP,
    const int* __restrict__ rowN, int* __restrict__ gh, int* __restrict__ tot){
  __shared__ int hist[1024];
  int mc = blockIdx.x;
  int m = mc >= NCH;
  int c = mc - m*NCH;
  const int* rowm = m ? rowN : rowP;
  int base = c*CHK;
  int n = min(CHK, NNZV - base);
  int t = threadIdx.x;
  for (int i = t; i < 1024; i += 256) hist[i] = 0;
  __syncthreads();
  for (int k = 0; k < CHK/256; ++k){
    int i = t + k*256;
    if (i < n) atomicAdd(&hist[rowm[base+i] >> 7], 1);
  }
  __syncthreads();
  for (int b = t; b < NB; b += 256){
    gh[mc*NB + b] = hist[b];
    atomicAdd(&tot[m*NB + b], hist[b]);
  }
}

// fused: global scan of tot (redundant per block, LDS) + per-(chunk,bucket)
// offsets (wave per (m,b)); block 0 also writes bbase for rsort.
__global__ __launch_bounds__(256) void k_boff(const int* __restrict__ tot,
    int* __restrict__ bbase, int* __restrict__ gh){
  __shared__ int ts[256];
  __shared__ int sc[2*NB];
  int t = threadIdx.x;
  int v[7]; int ssum = 0;
  #pragma unroll
  for (int j = 0; j < 7; ++j){
    int idx = t*7 + j;
    v[j] = (idx < 2*NB) ? tot[idx] : 0;
    ssum += v[j];
  }
  ts[t] = ssum; __syncthreads();
  for (int off = 1; off < 256; off <<= 1){
    int x = (t >= off) ? ts[t-off] : 0;
    __syncthreads();
    ts[t] += x;
    __syncthreads();
  }
  int run = ts[t] - ssum;
  #pragma unroll
  for (int j = 0; j < 7; ++j){
    int idx = t*7 + j;
    if (idx < 2*NB){
      sc[idx] = run;
      if (blockIdx.x == 0){
        int m = idx / NB, b = idx - m*NB;
        bbase[m*(NB+1) + b] = run - m*NNZV;
      }
      run += v[j];
    }
  }
  if (blockIdx.x == 0 && t == 0){ bbase[NB] = NNZV; bbase[(NB+1) + NB] = NNZV; }
  __syncthreads();
  int wid = blockIdx.x*4 + (t >> 6);
  if (wid >= 2*NB) return;
  int m = wid / NB, b = wid - m*NB;
  int lane = t & 63;
  int run2 = sc[wid] - m*NNZV;
  for (int c0 = 0; c0 < NCH; c0 += 64){
    int c = c0 + lane;
    int vv = (c < NCH) ? gh[(m*NCH + c)*NB + b] : 0;
    int inc = vv;
    #pragma unroll
    for (int d = 1; d < 64; d <<= 1){
      int y = __shfl_up(inc, d);
      if (lane >= d) inc += y;
    }
    if (c < NCH) gh[(m*NCH + c)*NB + b] = run2 + (inc - vv);
    run2 += __shfl(inc, 63);
  }
}

// counting-sort scatter: block = (m,c); deterministic dst, coalesced writes.
// pack: x = (col<<7) | ((row&127)<<24)   (col<<7 = byte offset into hb)
__global__ __launch_bounds__(256) void k_psort(
    const int* __restrict__ rowP, const int* __restrict__ colP, const float* __restrict__ valP,
    const int* __restrict__ rowN, const int* __restrict__ colN, const float* __restrict__ valN,
    const int* __restrict__ gh, int2* __restrict__ tmpP, int2* __restrict__ tmpN){
  __shared__ int hist[1024];
  __shared__ int start[1024];
  __shared__ int cur[1024];
  __shared__ int ogl[1024];
  __shared__ int ts[256];
  __shared__ unsigned short s_bin[CHK];
  __shared__ int2 s_ent[CHK];
  int mc = blockIdx.x;
  int m = mc >= NCH;
  int c = mc - m*NCH;
  const int* rowm = m ? rowN : rowP;
  const int* colm = m ? colN : colP;
  const float* valm = m ? valN : valP;
  int2* tmpm = m ? tmpN : tmpP;
  int base = c*CHK;
  int n = min(CHK, NNZV - base);
  int t = threadIdx.x;
  for (int i = t; i < 1024; i += 256) hist[i] = 0;
  __syncthreads();
  int rrow[CHK/256];
  #pragma unroll
  for (int k = 0; k < CHK/256; ++k){
    int i = t + k*256;
    rrow[k] = -1;
    if (i < n){
      rrow[k] = rowm[base+i];
      atomicAdd(&hist[rrow[k] >> 7], 1);
    }
  }
  __syncthreads();
  {
    int h0 = hist[4*t+0], h1 = hist[4*t+1], h2 = hist[4*t+2], h3 = hist[4*t+3];
    int s = h0+h1+h2+h3;
    ts[t] = s; __syncthreads();
    for (int off = 1; off < 256; off <<= 1){
      int x = (t >= off) ? ts[t-off] : 0;
      __syncthreads();
      ts[t] += x;
      __syncthreads();
    }
    int excl = ts[t] - s;
    start[4*t+0] = excl;            cur[4*t+0] = excl;
    start[4*t+1] = excl+h0;         cur[4*t+1] = excl+h0;
    start[4*t+2] = excl+h0+h1;      cur[4*t+2] = excl+h0+h1;
    start[4*t+3] = excl+h0+h1+h2;   cur[4*t+3] = excl+h0+h1+h2;
    for (int b = t; b < NB; b += 256) ogl[b] = gh[mc*NB + b];
  }
  __syncthreads();
  #pragma unroll
  for (int k = 0; k < CHK/256; ++k){
    int i = t + k*256;
    if (i < n){
      int r = rrow[k];
      int b = r >> 7;
      int pos = atomicAdd(&cur[b], 1);
      int2 e; e.x = (colm[base+i] << 7) | ((r & 127) << 24);
      e.y = __builtin_bit_cast(int, valm[base+i]);
      s_ent[pos] = e;
      s_bin[pos] = (unsigned short)b;
    }
  }
  __syncthreads();
  #pragma unroll
  for (int k = 0; k < CHK/256; ++k){
    int j = t + k*256;
    if (j < n){
      int b = s_bin[j];
      tmpm[ogl[b] + (j - start[b])] = s_ent[j];
    }
  }
}

// row sort within bucket -> padded CSR (rows padded to x16 with zero entries).
__global__ __launch_bounds__(256) void k_rsort(const int* __restrict__ bbase,
    const int2* __restrict__ tmpP, const int2* __restrict__ tmpN,
    int2* __restrict__ csvP, int2* __restrict__ csvN,
    int* __restrict__ rpsP, int* __restrict__ rpsN,
    int* __restrict__ rplP, int* __restrict__ rplN){
  __shared__ int hist[128];
  __shared__ int pst[128];
  __shared__ int cur[128];
  int m = blockIdx.x >= NB;
  int b = blockIdx.x - m*NB;
  const int2* tmp = m ? tmpN : tmpP;
  int2* csv = m ? csvN : csvP;
  int* rps = m ? rpsN : rpsP;
  int* rpl = m ? rplN : rplP;
  int s = bbase[m*(NB+1) + b];
  int e = bbase[m*(NB+1) + b + 1];
  int pbase = s + b*PADB;
  int t = threadIdx.x;
  if (t < 128) hist[t] = 0;
  __syncthreads();
  for (int i = s + t; i < e; i += 256)
    atomicAdd(&hist[(tmp[i].x >> 24) & 127], 1);
  __syncthreads();
  if (t < 64){
    int l0 = hist[2*t], l1 = hist[2*t+1];
    int p0 = (l0+15) & ~15, p1 = (l1+15) & ~15;
    int sum = p0 + p1;
    int inc = sum;
    #pragma unroll
    for (int d = 1; d < 64; d <<= 1){
      int y = __shfl_up(inc, d);
      if (t >= d) inc += y;
    }
    int excl = inc - sum;
    pst[2*t]   = excl;      cur[2*t]   = excl;
    pst[2*t+1] = excl + p0; cur[2*t+1] = excl + p0;
  }
  __syncthreads();
  if (t < 128){
    int row = (b << 7) + t;
    if (row < NN){
      rps[row] = pbase + pst[t];
      rpl[row] = (hist[t]+15) & ~15;
    }
  }
  for (int i = s + t; i < e; i += 256){
    int2 en = tmp[i];
    int rl = (en.x >> 24) & 127;
    int pos = atomicAdd(&cur[rl], 1);
    int2 o; o.x = en.x & 0x00FFFFFF; o.y = en.y;
    csv[pbase + pos] = o;
  }
  if (t < 128){
    int len = hist[t], plen = (len+15) & ~15;
    int2 z; z.x = 0; z.y = 0;
    for (int i = pst[t] + len; i < pst[t] + plen; ++i)
      csv[pbase + i] = z;
  }
}

// ---------------- h0 = tanh(x @ Wi + bi) ----------------
__global__ __launch_bounds__(256) void k_init(const float* __restrict__ x,
    const float* __restrict__ Wi, const float* __restrict__ bi,
    unsigned short* __restrict__ hb){
  __shared__ unsigned short At[64*128];
  __shared__ unsigned short Bt[64*128];
  const int t = threadIdx.x;
  const int row0 = blockIdx.x * 64;
  {
    int col = t & 63, kc = t >> 6;
    for (int k2 = 0; k2 < 32; ++k2){
      int k = kc*32 + k2;
      Bt[swzi<256>(col, k*2)] = f2b(Wi[k*64 + col]);
    }
  }
  {
    int r = t >> 2, q = t & 3;
    int rr = row0 + r; if (rr >= NN) rr = NN - 1;
    const float* xp = x + (size_t)rr*128 + q*32;
    for (int j = 0; j < 4; ++j){
      float4 a = *(const float4*)(xp + j*8);
      float4 b = *(const float4*)(xp + j*8 + 4);
      us8 v;
      v[0]=f2b(a.x); v[1]=f2b(a.y); v[2]=f2b(a.z); v[3]=f2b(a.w);
      v[4]=f2b(b.x); v[5]=f2b(b.y); v[6]=f2b(b.z); v[7]=f2b(b.w);
      *(us8*)&At[swzi<256>(r, q*64 + j*16)] = v;
    }
  }
  __syncthreads();
  const int lane = t & 63, w = t >> 6, g = lane >> 4, r16 = lane & 15;
  f32x4 zv = {0.f,0.f,0.f,0.f};
  f32x4 acc[4] = {zv, zv, zv, zv};
  #pragma unroll
  for (int it = 0; it < 4; ++it){
    int kb = it*32 + g*8;
    bf16x8 a = *(bf16x8*)&At[swzi<256>(w*16 + r16, kb*2)];
    #pragma unroll
    for (int nt = 0; nt < 4; ++nt){
      bf16x8 b = *(bf16x8*)&Bt[swzi<256>(nt*16 + r16, kb*2)];
      acc[nt] = __builtin_amdgcn_mfma_f32_16x16x32_bf16(a, b, acc[nt], 0, 0, 0);
    }
  }
  #pragma unroll
  for (int nt = 0; nt < 4; ++nt){
    int col = nt*16 + r16;
    float bv = bi[col];
    #pragma unroll
    for (int q = 0; q < 4; ++q){
      int row = w*16 + g*4 + q;
      if (row0 + row < NN)
        hb[(size_t)(row0+row)*64 + col] = f2b(ftanh(acc[nt][q] + bv));
    }
  }
}

// ------- spmm: wave per (row,sign); padded rows -> guard-free inner loop;
// ------- byte-offset cols (no 64-bit mul); bf16 output.
__global__ __launch_bounds__(256) void k_spmm(
    const int* __restrict__ rpsP, const int* __restrict__ rplP, const int2* __restrict__ csvP,
    const int* __restrict__ rpsN, const int* __restrict__ rplN, const int2* __restrict__ csvN,
    const unsigned short* __restrict__ hb,
    unsigned short* __restrict__ hpb, unsigned short* __restrict__ hnb){
  int wid = blockIdx.x*4 + (threadIdx.x >> 6);
  int lane = threadIdx.x & 63;
  int isNeg = (wid >= NN);
  int r = wid - (isNeg ? NN : 0);
  if (r >= NN) return;
  const int*  rps = isNeg ? rpsN : rpsP;
  const int*  rpl = isNeg ? rplN : rplP;
  const int2* csv = isNeg ? csvN : csvP;
  const char* hbb = (const char*)hb;
  int s = rps[r], plen = rpl[r];
  const int g = lane >> 3, c8 = lane & 7;
  float a[8];
  #pragma unroll
  for (int j = 0; j < 8; ++j) a[j] = 0.f;
  if (plen > 0){
    int e = s + plen;
    int2 cvA = csv[s + g];
    int2 cvB = csv[s + 8 + g];
    us8 hA = *(const us8*)(hbb + (unsigned)cvA.x + c8*16);
    us8 hB = *(const us8*)(hbb + (unsigned)cvB.x + c8*16);
    for (int base = s + 16; ; base += 16){
      bool more = base < e;          // wave-uniform
      int2 cvC, cvD;
      if (more){
        cvC = csv[base + g];
        cvD = csv[base + 8 + g];
      }
      float vA = __builtin_bit_cast(float, cvA.y);
      #pragma unroll
      for (int j = 0; j < 8; ++j) a[j] = fmaf(vA, b2f(hA[j]), a[j]);
      float vB = __builtin_bit_cast(float, cvB.y);
      #pragma unroll
      for (int j = 0; j < 8; ++j) a[j] = fmaf(vB, b2f(hB[j]), a[j]);
      if (!more) break;
      cvA = cvC; cvB = cvD;
      hA = *(const us8*)(hbb + (unsigned)cvA.x + c8*16);
      hB = *(const us8*)(hbb + (unsigned)cvB.x + c8*16);
    }
  }
  #pragma unroll
  for (int msk = 8; msk < 64; msk <<= 1){
    #pragma unroll
    for (int j = 0; j < 8; ++j) a[j] += __shfl_xor(a[j], msk);
  }
  if (g == 0){
    us8 o;
    #pragma unroll
    for (int j = 0; j < 8; ++j) o[j] = f2b(a[j]);
    *(us8*)&((isNeg ? hnb : hpb)[(size_t)r*64 + c8*8]) = o;
  }
}

// ---------------- gate + combine + out GEMM (one hop; bf16 hp/hn in) --------
__global__ __launch_bounds__(256) void k_gate(const unsigned short* __restrict__ hpb,
    const unsigned short* __restrict__ hnb, const float* __restrict__ Wg,
    const float* __restrict__ bg, const float* __restrict__ Wo,
    const float* __restrict__ bo, unsigned short* __restrict__ hb){
  __shared__ unsigned short A1[64*128];
  __shared__ unsigned short B1[64*128];
  __shared__ unsigned short A2[64*64];
  __shared__ unsigned short B2[64*64];
  const int t = threadIdx.x;
  const int row0 = blockIdx.x * 64;
  {
    int col = t & 63, kc = t >> 6;
    for (int k2 = 0; k2 < 32; ++k2){
      int k = kc*32 + k2;
      B1[swzi<256>(col, k*2)] = f2b(Wg[k*64 + col]);
    }
    for (int k2 = 0; k2 < 16; ++k2){
      int k = kc*16 + k2;
      B2[swzi<128>(col, k*2)] = f2b(Wo[k*64 + col]);
    }
  }
  {
    int r = t >> 2, q = t & 3;
    int rr = row0 + r; if (rr >= NN) rr = NN - 1;
    const unsigned short* src = (q < 2 ? hpb : hnb) + (size_t)rr*64 + (q & 1)*32;
    for (int j = 0; j < 4; ++j){
      us8 v = *(const us8*)(src + j*8);
      *(us8*)&A1[swzi<256>(r, q*64 + j*16)] = v;
    }
  }
  __syncthreads();
  const int lane = t & 63, w = t >> 6, g = lane >> 4, r16 = lane & 15;
  f32x4 zv = {0.f,0.f,0.f,0.f};
  f32x4 acc[4] = {zv, zv, zv, zv};
  #pragma unroll
  for (int it = 0; it < 4; ++it){
    int kb = it*32 + g*8;
    bf16x8 a = *(bf16x8*)&A1[swzi<256>(w*16 + r16, kb*2)];
    #pragma unroll
    for (int nt = 0; nt < 4; ++nt){
      bf16x8 b = *(bf16x8*)&B1[swzi<256>(nt*16 + r16, kb*2)];
      acc[nt] = __builtin_amdgcn_mfma_f32_16x16x32_bf16(a, b, acc[nt], 0, 0, 0);
    }
  }
  #pragma unroll
  for (int nt = 0; nt < 4; ++nt){
    int col = nt*16 + r16;
    float bgv = bg[col];
    #pragma unroll
    for (int q = 0; q < 4; ++q){
      int row = w*16 + g*4 + q;
      float gg  = fsigm(acc[nt][q] + bgv);
      float hpv = b2f(A1[swzi<256>(row, col*2)]);
      float hnv = b2f(A1[swzi<256>(row, (64+col)*2)]);
      A2[swzi<128>(row, col*2)] = f2b(gg*hpv + (1.f-gg)*hnv);
    }
  }
  f32x4 acc2[4] = {zv, zv, zv, zv};
  #pragma unroll
  for (int it = 0; it < 2; ++it){
    int kb = it*32 + g*8;
    bf16x8 a = *(bf16x8*)&A2[swzi<128>(w*16 + r16, kb*2)];
    #pragma unroll
    for (int nt = 0; nt < 4; ++nt){
      bf16x8 b = *(bf16x8*)&B2[swzi<128>(nt*16 + r16, kb*2)];
      acc2[nt] = __builtin_amdgcn_mfma_f32_16x16x32_bf16(a, b, acc2[nt], 0, 0, 0);
    }
  }
  #pragma unroll
  for (int nt = 0; nt < 4; ++nt){
    int col = nt*16 + r16;
    float bv = bo[col];
    #pragma unroll
    for (int q = 0; q < 4; ++q){
      int row = w*16 + g*4 + q;
      if (row0 + row < NN)
        hb[(size_t)(row0+row)*64 + col] = f2b(ftanh(acc2[nt][q] + bv));
    }
  }
}

// ---- edge MLP: barrier'd collaborative staging (L2 reuse), slim LDS,
// ---- B-fragments for kt=0..3 hoisted to registers, in-register |d|/m.
__global__ __launch_bounds__(256, 3) void k_edge(const int* __restrict__ ei,
    const unsigned short* __restrict__ hb, const float* __restrict__ We1,
    const float* __restrict__ be1, const float* __restrict__ We2,
    const float* __restrict__ be2, float* __restrict__ out){
  __shared__ unsigned short Hu[64*64];    // 8KB, swzi<128>
  __shared__ unsigned short Hv[64*64];    // 8KB
  __shared__ unsigned short Bt[64*256];   // 32KB, swzi<512>
  const int t = threadIdx.x;
  {
    int col = t & 63, kc = t >> 6;
    for (int k2 = 0; k2 < 64; ++k2){
      int k = kc*64 + k2;
      Bt[swzi<512>(col, k*2)] = f2b(We1[k*64 + col]);
    }
  }
  __syncthreads();
  const int lane = t & 63, w = t >> 6, g = lane >> 4, r16 = lane & 15;
  const int r = t >> 2, q = t & 3;
  const float be2v = be2[0];
  float be1v[4], we2v[4];
  #pragma unroll
  for (int nt = 0; nt < 4; ++nt){
    be1v[nt] = be1[nt*16 + r16];
    we2v[nt] = We2[nt*16 + r16];
  }
  bf16x8 Bh[4][4];
  #pragma unroll
  for (int kt = 0; kt < 4; ++kt){
    #pragma unroll
    for (int nt = 0; nt < 4; ++nt)
      Bh[kt][nt] = *(bf16x8*)&Bt[swzi<512>(nt*16 + r16, (kt*32 + g*8)*2)];
  }
  const int NT = EE/64;
  int tile = blockIdx.x;
  int u = 0, v = 0;
  if (tile < NT){
    u = ei[tile*64 + r];
    v = ei[EE + tile*64 + r];
  }
  for (; tile < NT; tile += gridDim.x){
    const unsigned short* pu = hb + (size_t)u*64 + q*16;
    const unsigned short* pv = hb + (size_t)v*64 + q*16;
    us8 a0 = *(const us8*)pu;
    us8 a1 = *(const us8*)(pu + 8);
    us8 b0 = *(const us8*)pv;
    us8 b1 = *(const us8*)(pv + 8);
    int nt2 = tile + gridDim.x;
    if (nt2 < NT){
      u = ei[nt2*64 + r];
      v = ei[EE + nt2*64 + r];
    }
    *(us8*)&Hu[swzi<128>(r, q*32)]      = a0;
    *(us8*)&Hu[swzi<128>(r, q*32 + 16)] = a1;
    *(us8*)&Hv[swzi<128>(r, q*32)]      = b0;
    *(us8*)&Hv[swzi<128>(r, q*32 + 16)] = b1;
    __syncthreads();
    int arow = w*16 + r16;
    us8 huL = *(us8*)&Hu[swzi<128>(arow, g*16)];
    us8 huH = *(us8*)&Hu[swzi<128>(arow, 64 + g*16)];
    us8 hvL = *(us8*)&Hv[swzi<128>(arow, g*16)];
    us8 hvH = *(us8*)&Hv[swzi<128>(arow, 64 + g*16)];
    us8 dL, dH, mL, mH;
    #pragma unroll
    for (int j = 0; j < 8; ++j){
      float x0 = b2f(huL[j]), y0 = b2f(hvL[j]);
      float x1 = b2f(huH[j]), y1 = b2f(hvH[j]);
      dL[j] = f2b(fabsf(x0 - y0)); dH[j] = f2b(fabsf(x1 - y1));
      mL[j] = f2b(x0 * y0);        mH[j] = f2b(x1 * y1);
    }
    f32x4 zv = {0.f,0.f,0.f,0.f};
    f32x4 acc[4] = {zv, zv, zv, zv};
    #pragma unroll
    for (int kt = 0; kt < 4; ++kt){
      us8 ra;
      switch (kt){
        case 0: ra = huL; break;
        case 1: ra = huH; break;
        case 2: ra = hvL; break;
        default: ra = hvH; break;
      }
      bf16x8 a = __builtin_bit_cast(bf16x8, ra);
      #pragma unroll
      for (int nt = 0; nt < 4; ++nt)
        acc[nt] = __builtin_amdgcn_mfma_f32_16x16x32_bf16(a, Bh[kt][nt], acc[nt], 0, 0, 0);
    }
    #pragma unroll
    for (int kt = 4; kt < 8; ++kt){
      us8 ra;
      switch (kt){
        case 4: ra = dL; break;
        case 5: ra = dH; break;
        case 6: ra = mL; break;
        default: ra = mH; break;
      }
      bf16x8 a = __builtin_bit_cast(bf16x8, ra);
      int kb = kt*32 + g*8;
      #pragma unroll
      for (int nt = 0; nt < 4; ++nt){
        bf16x8 b = *(bf16x8*)&Bt[swzi<512>(nt*16 + r16, kb*2)];
        acc[nt] = __builtin_amdgcn_mfma_f32_16x16x32_bf16(a, b, acc[nt], 0, 0, 0);
      }
    }
    float p0 = 0.f, p1 = 0.f, p2 = 0.f, p3 = 0.f;
    #pragma unroll
    for (int nt = 0; nt < 4; ++nt){
      float bb = be1v[nt], w2 = we2v[nt];
      p0 += fmaxf(acc[nt][0] + bb, 0.f) * w2;
      p1 += fmaxf(acc[nt][1] + bb, 0.f) * w2;
      p2 += fmaxf(acc[nt][2] + bb, 0.f) * w2;
      p3 += fmaxf(acc[nt][3] + bb, 0.f) * w2;
    }
    #pragma unroll
    for (int m = 1; m < 16; m <<= 1){
      p0 += __shfl_xor(p0, m);
      p1 += __shfl_xor(p1, m);
      p2 += __shfl_xor(p2, m);
      p3 += __shfl_xor(p3, m);
    }
    if (r16 == 0){
      int eb = tile*64 + w*16 + g*4;
      out[eb+0] = p0 + be2v;
      out[eb+1] = p1 + be2v;
      out[eb+2] = p2 + be2v;
      out[eb+3] = p3 + be2v;
    }
    __syncthreads();
  }
}

extern "C" void kernel_launch(void* const* d_in, const int* in_sizes, int n_in,
                              void* d_out, int out_size, void* d_ws, size_t ws_size,
                              hipStream_t stream){
  (void)in_sizes; (void)n_in; (void)out_size; (void)ws_size;
  const float* x       = (const float*)d_in[0];
  const int*   pos_row = (const int*)d_in[1];
  const int*   pos_col = (const int*)d_in[2];
  const float* pos_val = (const float*)d_in[3];
  const int*   neg_row = (const int*)d_in[4];
  const int*   neg_col = (const int*)d_in[5];
  const float* neg_val = (const float*)d_in[6];
  const int*   ei      = (const int*)d_in[7];
  const float* Wi      = (const float*)d_in[8];
  const float* bi      = (const float*)d_in[9];
  const float* Wg      = (const float*)d_in[10];
  const float* bg      = (const float*)d_in[11];
  const float* Wo      = (const float*)d_in[12];
  const float* bo      = (const float*)d_in[13];
  const float* We1     = (const float*)d_in[14];
  const float* be1     = (const float*)d_in[15];
  const float* We2     = (const float*)d_in[16];
  const float* be2     = (const float*)d_in[17];
  float* out = (float*)d_out;

  char* ws = (char*)d_ws;
  size_t off = 0;
  auto alloc = [&](size_t b)->char*{
    char* p = ws + off; off = (off + b + 255) & ~(size_t)255; return p;
  };
  const size_t CSVN = (size_t)NNZV + (size_t)NB*PADB;
  unsigned short* hb  = (unsigned short*)alloc((size_t)NN*64*2);
  unsigned short* hpb = (unsigned short*)alloc((size_t)NN*64*2);
  unsigned short* hnb = (unsigned short*)alloc((size_t)NN*64*2);
  int2*  tmpP = (int2*)alloc((size_t)NNZV*8);
  int2*  tmpN = (int2*)alloc((size_t)NNZV*8);
  int2*  csvP = (int2*)alloc(CSVN*8);
  int2*  csvN = (int2*)alloc(CSVN*8);
  int*   rpsP = (int*)alloc((size_t)NN*4);
  int*   rpsN = (int*)alloc((size_t)NN*4);
  int*   rplP = (int*)alloc((size_t)NN*4);
  int*   rplN = (int*)alloc((size_t)NN*4);
  int*   gh   = (int*)alloc((size_t)2*NCH*NB*4);
  int*   tot  = (int*)alloc((size_t)2*NB*4);
  int*   bbase= (int*)alloc((size_t)2*(NB+1)*4);

  hipMemsetAsync(tot, 0, (size_t)2*NB*4, stream);
  k_bhist<<<2*NCH, 256, 0, stream>>>(pos_row, neg_row, gh, tot);
  k_boff<<<(2*NB+3)/4, 256, 0, stream>>>(tot, bbase, gh);
  k_psort<<<2*NCH, 256, 0, stream>>>(pos_row, pos_col, pos_val,
                                     neg_row, neg_col, neg_val,
                                     gh, tmpP, tmpN);
  k_rsort<<<2*NB, 256, 0, stream>>>(bbase, tmpP, tmpN, csvP, csvN,
                                    rpsP, rpsN, rplP, rplN);
  k_init<<<(NN+63)/64, 256, 0, stream>>>(x, Wi, bi, hb);
  for (int hop = 0; hop < 2; ++hop){
    k_spmm<<<(2*NN+3)/4, 256, 0, stream>>>(rpsP, rplP, csvP,
                                           rpsN, rplN, csvN, hb, hpb, hnb);
    k_gate<<<(NN+63)/64, 256, 0, stream>>>(hpb, hnb,
        Wg + (size_t)hop*128*64, bg + (size_t)hop*64,
        Wo + (size_t)hop*64*64,  bo + (size_t)hop*64, hb);
  }
  k_edge<<<2048, 256, 0, stream>>>(ei, hb, We1, be1, We2, be2, out);
}

// Round 16
// 359.582 us; speedup vs baseline: 1.0458x; 1.0458x over previous
//
#include <hip/hip_runtime.h>

#define NN 100000
#define NNZV 1600000
#define EE 1000000
#define NB 782              // row buckets of 128 rows
#define CHK 4096            // entries per sort chunk
#define NCH 391             // chunks per matrix (391*4096 >= 1.6M)

typedef __attribute__((ext_vector_type(4))) float f32x4;
typedef __attribute__((ext_vector_type(8))) short bf16x8;
typedef __attribute__((ext_vector_type(8))) unsigned short us8;

__device__ __forceinline__ unsigned short f2b(float f){
  unsigned int u = __builtin_bit_cast(unsigned int, f);
  u += 0x7FFFu + ((u >> 16) & 1u);
  return (unsigned short)(u >> 16);
}
__device__ __forceinline__ float b2f(unsigned short s){
  unsigned int u = ((unsigned int)s) << 16;
  return __builtin_bit_cast(float, u);
}
__device__ __forceinline__ float ftanh(float x){
  x = fminf(15.f, fmaxf(-15.f, x));
  float e = __expf(2.f * x);
  return (e - 1.f) / (e + 1.f);
}
__device__ __forceinline__ float fsigm(float x){
  x = fminf(30.f, fmaxf(-30.f, x));
  return 1.f / (1.f + __expf(-x));
}

// XOR swizzle in 16B units within a row of RB bytes; returns ushort index.
template<int RB>
__device__ __forceinline__ int swzi(int row, int kbyte){
  constexpr int UM = (RB/16 - 1) < 15 ? (RB/16 - 1) : 15;
  int unit = (kbyte >> 4) ^ (row & UM);
  return (row*RB + (unit << 4) + (kbyte & 15)) >> 1;
}

// ============ bucket-sort build (deterministic) ============

// per-chunk bucket histogram + global bucket totals (non-returning int atomics)
__global__ __launch_bounds__(256) void k_bhist(const int* __restrict__ rowP,
    const int* __restrict__ rowN, int* __restrict__ gh, int* __restrict__ tot){
  __shared__ int hist[1024];
  int mc = blockIdx.x;
  int m = mc >= NCH;
  int c = mc - m*NCH;
  const int* rowm = m ? rowN : rowP;
  int base = c*CHK;
  int n = min(CHK, NNZV - base);
  int t = threadIdx.x;
  for (int i = t; i < 1024; i += 256) hist[i] = 0;
  __syncthreads();
  for (int k = 0; k < CHK/256; ++k){
    int i = t + k*256;
    if (i < n) atomicAdd(&hist[rowm[base+i] >> 7], 1);
  }
  __syncthreads();
  for (int b = t; b < NB; b += 256){
    gh[mc*NB + b] = hist[b];
    atomicAdd(&tot[m*NB + b], hist[b]);
  }
}

// fused: global scan of tot (redundant per block, LDS) + per-(chunk,bucket)
// offsets (wave per (m,b)); block 0 also writes bbase for rsort.
__global__ __launch_bounds__(256) void k_boff(const int* __restrict__ tot,
    int* __restrict__ bbase, int* __restrict__ gh){
  __shared__ int ts[256];
  __shared__ int sc[2*NB];
  int t = threadIdx.x;
  int v[7]; int ssum = 0;
  #pragma unroll
  for (int j = 0; j < 7; ++j){
    int idx = t*7 + j;
    v[j] = (idx < 2*NB) ? tot[idx] : 0;
    ssum += v[j];
  }
  ts[t] = ssum; __syncthreads();
  for (int off = 1; off < 256; off <<= 1){
    int x = (t >= off) ? ts[t-off] : 0;
    __syncthreads();
    ts[t] += x;
    __syncthreads();
  }
  int run = ts[t] - ssum;
  #pragma unroll
  for (int j = 0; j < 7; ++j){
    int idx = t*7 + j;
    if (idx < 2*NB){
      sc[idx] = run;
      if (blockIdx.x == 0){
        int m = idx / NB, b = idx - m*NB;
        bbase[m*(NB+1) + b] = run - m*NNZV;
      }
      run += v[j];
    }
  }
  if (blockIdx.x == 0 && t == 0){ bbase[NB] = NNZV; bbase[(NB+1) + NB] = NNZV; }
  __syncthreads();
  int wid = blockIdx.x*4 + (t >> 6);
  if (wid >= 2*NB) return;
  int m = wid / NB, b = wid - m*NB;
  int lane = t & 63;
  int run2 = sc[wid] - m*NNZV;
  for (int c0 = 0; c0 < NCH; c0 += 64){
    int c = c0 + lane;
    int vv = (c < NCH) ? gh[(m*NCH + c)*NB + b] : 0;
    int inc = vv;
    #pragma unroll
    for (int d = 1; d < 64; d <<= 1){
      int y = __shfl_up(inc, d);
      if (lane >= d) inc += y;
    }
    if (c < NCH) gh[(m*NCH + c)*NB + b] = run2 + (inc - vv);
    run2 += __shfl(inc, 63);
  }
}

// counting-sort scatter: block = (m,c); deterministic dst, coalesced writes.
// pack: x = col | ((row&127)<<17), y = val bits
__global__ __launch_bounds__(256) void k_psort(
    const int* __restrict__ rowP, const int* __restrict__ colP, const float* __restrict__ valP,
    const int* __restrict__ rowN, const int* __restrict__ colN, const float* __restrict__ valN,
    const int* __restrict__ gh, int2* __restrict__ tmpP, int2* __restrict__ tmpN){
  __shared__ int hist[1024];
  __shared__ int start[1024];
  __shared__ int cur[1024];
  __shared__ int ogl[1024];
  __shared__ int ts[256];
  __shared__ unsigned short s_bin[CHK];
  __shared__ int2 s_ent[CHK];
  int mc = blockIdx.x;
  int m = mc >= NCH;
  int c = mc - m*NCH;
  const int* rowm = m ? rowN : rowP;
  const int* colm = m ? colN : colP;
  const float* valm = m ? valN : valP;
  int2* tmpm = m ? tmpN : tmpP;
  int base = c*CHK;
  int n = min(CHK, NNZV - base);
  int t = threadIdx.x;
  for (int i = t; i < 1024; i += 256) hist[i] = 0;
  __syncthreads();
  int rrow[CHK/256];
  #pragma unroll
  for (int k = 0; k < CHK/256; ++k){
    int i = t + k*256;
    rrow[k] = -1;
    if (i < n){
      rrow[k] = rowm[base+i];
      atomicAdd(&hist[rrow[k] >> 7], 1);
    }
  }
  __syncthreads();
  {
    int h0 = hist[4*t+0], h1 = hist[4*t+1], h2 = hist[4*t+2], h3 = hist[4*t+3];
    int s = h0+h1+h2+h3;
    ts[t] = s; __syncthreads();
    for (int off = 1; off < 256; off <<= 1){
      int x = (t >= off) ? ts[t-off] : 0;
      __syncthreads();
      ts[t] += x;
      __syncthreads();
    }
    int excl = ts[t] - s;
    start[4*t+0] = excl;            cur[4*t+0] = excl;
    start[4*t+1] = excl+h0;         cur[4*t+1] = excl+h0;
    start[4*t+2] = excl+h0+h1;      cur[4*t+2] = excl+h0+h1;
    start[4*t+3] = excl+h0+h1+h2;   cur[4*t+3] = excl+h0+h1+h2;
    for (int b = t; b < NB; b += 256) ogl[b] = gh[mc*NB + b];
  }
  __syncthreads();
  #pragma unroll
  for (int k = 0; k < CHK/256; ++k){
    int i = t + k*256;
    if (i < n){
      int r = rrow[k];
      int b = r >> 7;
      int pos = atomicAdd(&cur[b], 1);
      int2 e; e.x = colm[base+i] | ((r & 127) << 17);
      e.y = __builtin_bit_cast(int, valm[base+i]);
      s_ent[pos] = e;
      s_bin[pos] = (unsigned short)b;
    }
  }
  __syncthreads();
  #pragma unroll
  for (int k = 0; k < CHK/256; ++k){
    int j = t + k*256;
    if (j < n){
      int b = s_bin[j];
      tmpm[ogl[b] + (j - start[b])] = s_ent[j];
    }
  }
}

// fused: rsort (blocks 0..2*NB-1) + init GEMM (remaining blocks).
// LDS unioned: rsort uses 1.5KB, init uses 32KB.
__global__ __launch_bounds__(256) void k_rsini(const int* __restrict__ bbase,
    const int2* __restrict__ tmpP, const int2* __restrict__ tmpN,
    int2* __restrict__ csvP, int2* __restrict__ csvN,
    int* __restrict__ rpP, int* __restrict__ rpN,
    const float* __restrict__ x, const float* __restrict__ Wi,
    const float* __restrict__ bi, unsigned short* __restrict__ hb){
  __shared__ __align__(16) char smem[64*128*2*2];   // 32KB
  const int t = threadIdx.x;
  if (blockIdx.x < 2*NB){
    // ---------------- rsort role ----------------
    int* hist   = (int*)smem;
    int* sstart = hist + 128;
    int* cur    = sstart + 128;
    int m = blockIdx.x >= NB;
    int b = blockIdx.x - m*NB;
    const int2* tmp = m ? tmpN : tmpP;
    int2* csv = m ? csvN : csvP;
    int* rp = m ? rpN : rpP;
    int s = bbase[m*(NB+1) + b];
    int e = bbase[m*(NB+1) + b + 1];
    if (t < 128) hist[t] = 0;
    __syncthreads();
    for (int i = s + t; i < e; i += 256)
      atomicAdd(&hist[(tmp[i].x >> 17) & 127], 1);
    __syncthreads();
    if (t < 64){
      int x0 = hist[2*t], x1 = hist[2*t+1];
      int sum = x0 + x1;
      int inc = sum;
      #pragma unroll
      for (int d = 1; d < 64; d <<= 1){
        int y = __shfl_up(inc, d);
        if (t >= d) inc += y;
      }
      int excl = inc - sum;
      sstart[2*t]   = excl;      cur[2*t]   = excl;
      sstart[2*t+1] = excl + x0; cur[2*t+1] = excl + x0;
    }
    __syncthreads();
    if (t < 128){
      int row = (b << 7) + t;
      if (row < NN) rp[row] = s + sstart[t];
    }
    if (b == NB-1 && t == 0) rp[NN] = NNZV;
    for (int i = s + t; i < e; i += 256){
      int2 en = tmp[i];
      int rl = (en.x >> 17) & 127;
      int pos = atomicAdd(&cur[rl], 1);
      int2 o; o.x = en.x & 0x1FFFF; o.y = en.y;
      csv[s + pos] = o;
    }
    return;
  }
  // ---------------- init role: h0 = tanh(x @ Wi + bi) ----------------
  unsigned short* At = (unsigned short*)smem;
  unsigned short* Bt = At + 64*128;
  const int row0 = (blockIdx.x - 2*NB) * 64;
  {
    int col = t & 63, kc = t >> 6;
    for (int k2 = 0; k2 < 32; ++k2){
      int k = kc*32 + k2;
      Bt[swzi<256>(col, k*2)] = f2b(Wi[k*64 + col]);
    }
  }
  {
    int r = t >> 2, q = t & 3;
    int rr = row0 + r; if (rr >= NN) rr = NN - 1;
    const float* xp = x + (size_t)rr*128 + q*32;
    for (int j = 0; j < 4; ++j){
      float4 a = *(const float4*)(xp + j*8);
      float4 b = *(const float4*)(xp + j*8 + 4);
      us8 v;
      v[0]=f2b(a.x); v[1]=f2b(a.y); v[2]=f2b(a.z); v[3]=f2b(a.w);
      v[4]=f2b(b.x); v[5]=f2b(b.y); v[6]=f2b(b.z); v[7]=f2b(b.w);
      *(us8*)&At[swzi<256>(r, q*64 + j*16)] = v;
    }
  }
  __syncthreads();
  const int lane = t & 63, w = t >> 6, g = lane >> 4, r16 = lane & 15;
  f32x4 zv = {0.f,0.f,0.f,0.f};
  f32x4 acc[4] = {zv, zv, zv, zv};
  #pragma unroll
  for (int it = 0; it < 4; ++it){
    int kb = it*32 + g*8;
    bf16x8 a = *(bf16x8*)&At[swzi<256>(w*16 + r16, kb*2)];
    #pragma unroll
    for (int nt = 0; nt < 4; ++nt){
      bf16x8 b = *(bf16x8*)&Bt[swzi<256>(nt*16 + r16, kb*2)];
      acc[nt] = __builtin_amdgcn_mfma_f32_16x16x32_bf16(a, b, acc[nt], 0, 0, 0);
    }
  }
  #pragma unroll
  for (int nt = 0; nt < 4; ++nt){
    int col = nt*16 + r16;
    float bv = bi[col];
    #pragma unroll
    for (int q = 0; q < 4; ++q){
      int row = w*16 + g*4 + q;
      if (row0 + row < NN)
        hb[(size_t)(row0+row)*64 + col] = f2b(ftanh(acc[nt][q] + bv));
    }
  }
}

// ------- spmm: wave per (row,sign); 16-entry step, paired prologue gathers;
// ------- bf16 output (identical rounding to gate-side f2b).
__global__ __launch_bounds__(256) void k_spmm(
    const int* __restrict__ rpP, const int2* __restrict__ csvP,
    const int* __restrict__ rpN, const int2* __restrict__ csvN,
    const unsigned short* __restrict__ hb,
    unsigned short* __restrict__ hpb, unsigned short* __restrict__ hnb){
  int wid = blockIdx.x*4 + (threadIdx.x >> 6);
  int lane = threadIdx.x & 63;
  int isNeg = (wid >= NN);
  int r = wid - (isNeg ? NN : 0);
  if (r >= NN) return;
  const int*  rp  = isNeg ? rpN  : rpP;
  const int2* csv = isNeg ? csvN : csvP;
  int s = rp[r], e = rp[r+1];
  const int g = lane >> 3, c8 = lane & 7;
  float a[8];
  #pragma unroll
  for (int j = 0; j < 8; ++j) a[j] = 0.f;
  int2 cvA = {0,0}, cvB = {0,0};
  if (s + g < e)     cvA = csv[s + g];
  if (s + 8 + g < e) cvB = csv[s + 8 + g];
  us8 hA = *(const us8*)&hb[(size_t)cvA.x*64 + c8*8];
  us8 hB = *(const us8*)&hb[(size_t)cvB.x*64 + c8*8];
  for (int base = s; base < e; base += 16){
    int2 cvC = {0,0}, cvD = {0,0};
    if (base + 16 + g < e) cvC = csv[base + 16 + g];
    if (base + 24 + g < e) cvD = csv[base + 24 + g];
    float vA = __builtin_bit_cast(float, cvA.y);   // 0.0f for padded slots
    #pragma unroll
    for (int j = 0; j < 8; ++j) a[j] = fmaf(vA, b2f(hA[j]), a[j]);
    float vB = __builtin_bit_cast(float, cvB.y);
    #pragma unroll
    for (int j = 0; j < 8; ++j) a[j] = fmaf(vB, b2f(hB[j]), a[j]);
    cvA = cvC; cvB = cvD;
    hA = *(const us8*)&hb[(size_t)cvA.x*64 + c8*8];
    hB = *(const us8*)&hb[(size_t)cvB.x*64 + c8*8];
  }
  #pragma unroll
  for (int msk = 8; msk < 64; msk <<= 1){
    #pragma unroll
    for (int j = 0; j < 8; ++j) a[j] += __shfl_xor(a[j], msk);
  }
  if (g == 0){
    us8 o;
    #pragma unroll
    for (int j = 0; j < 8; ++j) o[j] = f2b(a[j]);
    *(us8*)&((isNeg ? hnb : hpb)[(size_t)r*64 + c8*8]) = o;
  }
}

// ---------------- gate + combine + out GEMM (one hop; bf16 hp/hn in) --------
__global__ __launch_bounds__(256) void k_gate(const unsigned short* __restrict__ hpb,
    const unsigned short* __restrict__ hnb, const float* __restrict__ Wg,
    const float* __restrict__ bg, const float* __restrict__ Wo,
    const float* __restrict__ bo, unsigned short* __restrict__ hb){
  __shared__ unsigned short A1[64*128];
  __shared__ unsigned short B1[64*128];
  __shared__ unsigned short A2[64*64];
  __shared__ unsigned short B2[64*64];
  const int t = threadIdx.x;
  const int row0 = blockIdx.x * 64;
  {
    int col = t & 63, kc = t >> 6;
    for (int k2 = 0; k2 < 32; ++k2){
      int k = kc*32 + k2;
      B1[swzi<256>(col, k*2)] = f2b(Wg[k*64 + col]);
    }
    for (int k2 = 0; k2 < 16; ++k2){
      int k = kc*16 + k2;
      B2[swzi<128>(col, k*2)] = f2b(Wo[k*64 + col]);
    }
  }
  {
    int r = t >> 2, q = t & 3;
    int rr = row0 + r; if (rr >= NN) rr = NN - 1;
    const unsigned short* src = (q < 2 ? hpb : hnb) + (size_t)rr*64 + (q & 1)*32;
    for (int j = 0; j < 4; ++j){
      us8 v = *(const us8*)(src + j*8);
      *(us8*)&A1[swzi<256>(r, q*64 + j*16)] = v;
    }
  }
  __syncthreads();
  const int lane = t & 63, w = t >> 6, g = lane >> 4, r16 = lane & 15;
  f32x4 zv = {0.f,0.f,0.f,0.f};
  f32x4 acc[4] = {zv, zv, zv, zv};
  #pragma unroll
  for (int it = 0; it < 4; ++it){
    int kb = it*32 + g*8;
    bf16x8 a = *(bf16x8*)&A1[swzi<256>(w*16 + r16, kb*2)];
    #pragma unroll
    for (int nt = 0; nt < 4; ++nt){
      bf16x8 b = *(bf16x8*)&B1[swzi<256>(nt*16 + r16, kb*2)];
      acc[nt] = __builtin_amdgcn_mfma_f32_16x16x32_bf16(a, b, acc[nt], 0, 0, 0);
    }
  }
  #pragma unroll
  for (int nt = 0; nt < 4; ++nt){
    int col = nt*16 + r16;
    float bgv = bg[col];
    #pragma unroll
    for (int q = 0; q < 4; ++q){
      int row = w*16 + g*4 + q;
      float gg  = fsigm(acc[nt][q] + bgv);
      float hpv = b2f(A1[swzi<256>(row, col*2)]);
      float hnv = b2f(A1[swzi<256>(row, (64+col)*2)]);
      A2[swzi<128>(row, col*2)] = f2b(gg*hpv + (1.f-gg)*hnv);
    }
  }
  f32x4 acc2[4] = {zv, zv, zv, zv};
  #pragma unroll
  for (int it = 0; it < 2; ++it){
    int kb = it*32 + g*8;
    bf16x8 a = *(bf16x8*)&A2[swzi<128>(w*16 + r16, kb*2)];
    #pragma unroll
    for (int nt = 0; nt < 4; ++nt){
      bf16x8 b = *(bf16x8*)&B2[swzi<128>(nt*16 + r16, kb*2)];
      acc2[nt] = __builtin_amdgcn_mfma_f32_16x16x32_bf16(a, b, acc2[nt], 0, 0, 0);
    }
  }
  #pragma unroll
  for (int nt = 0; nt < 4; ++nt){
    int col = nt*16 + r16;
    float bv = bo[col];
    #pragma unroll
    for (int q = 0; q < 4; ++q){
      int row = w*16 + g*4 + q;
      if (row0 + row < NN)
        hb[(size_t)(row0+row)*64 + col] = f2b(ftanh(acc2[nt][q] + bv));
    }
  }
}

// ---- edge MLP: barrier'd collaborative staging (L2 reuse), slim LDS,
// ---- B-fragments for kt=0..3 hoisted to registers, in-register |d|/m.
__global__ __launch_bounds__(256, 3) void k_edge(const int* __restrict__ ei,
    const unsigned short* __restrict__ hb, const float* __restrict__ We1,
    const float* __restrict__ be1, const float* __restrict__ We2,
    const float* __restrict__ be2, float* __restrict__ out){
  __shared__ unsigned short Hu[64*64];    // 8KB, swzi<128>
  __shared__ unsigned short Hv[64*64];    // 8KB
  __shared__ unsigned short Bt[64*256];   // 32KB, swzi<512>
  const int t = threadIdx.x;
  {
    int col = t & 63, kc = t >> 6;
    for (int k2 = 0; k2 < 64; ++k2){
      int k = kc*64 + k2;
      Bt[swzi<512>(col, k*2)] = f2b(We1[k*64 + col]);
    }
  }
  __syncthreads();
  const int lane = t & 63, w = t >> 6, g = lane >> 4, r16 = lane & 15;
  const int r = t >> 2, q = t & 3;
  const float be2v = be2[0];
  float be1v[4], we2v[4];
  #pragma unroll
  for (int nt = 0; nt < 4; ++nt){
    be1v[nt] = be1[nt*16 + r16];
    we2v[nt] = We2[nt*16 + r16];
  }
  bf16x8 Bh[4][4];
  #pragma unroll
  for (int kt = 0; kt < 4; ++kt){
    #pragma unroll
    for (int nt = 0; nt < 4; ++nt)
      Bh[kt][nt] = *(bf16x8*)&Bt[swzi<512>(nt*16 + r16, (kt*32 + g*8)*2)];
  }
  const int NT = EE/64;
  int tile = blockIdx.x;
  int u = 0, v = 0;
  if (tile < NT){
    u = ei[tile*64 + r];
    v = ei[EE + tile*64 + r];
  }
  for (; tile < NT; tile += gridDim.x){
    const unsigned short* pu = hb + (size_t)u*64 + q*16;
    const unsigned short* pv = hb + (size_t)v*64 + q*16;
    us8 a0 = *(const us8*)pu;
    us8 a1 = *(const us8*)(pu + 8);
    us8 b0 = *(const us8*)pv;
    us8 b1 = *(const us8*)(pv + 8);
    int nt2 = tile + gridDim.x;
    if (nt2 < NT){
      u = ei[nt2*64 + r];
      v = ei[EE + nt2*64 + r];
    }
    *(us8*)&Hu[swzi<128>(r, q*32)]      = a0;
    *(us8*)&Hu[swzi<128>(r, q*32 + 16)] = a1;
    *(us8*)&Hv[swzi<128>(r, q*32)]      = b0;
    *(us8*)&Hv[swzi<128>(r, q*32 + 16)] = b1;
    __syncthreads();
    int arow = w*16 + r16;
    us8 huL = *(us8*)&Hu[swzi<128>(arow, g*16)];
    us8 huH = *(us8*)&Hu[swzi<128>(arow, 64 + g*16)];
    us8 hvL = *(us8*)&Hv[swzi<128>(arow, g*16)];
    us8 hvH = *(us8*)&Hv[swzi<128>(arow, 64 + g*16)];
    us8 dL, dH, mL, mH;
    #pragma unroll
    for (int j = 0; j < 8; ++j){
      float x0 = b2f(huL[j]), y0 = b2f(hvL[j]);
      float x1 = b2f(huH[j]), y1 = b2f(hvH[j]);
      dL[j] = f2b(fabsf(x0 - y0)); dH[j] = f2b(fabsf(x1 - y1));
      mL[j] = f2b(x0 * y0);        mH[j] = f2b(x1 * y1);
    }
    f32x4 zv = {0.f,0.f,0.f,0.f};
    f32x4 acc[4] = {zv, zv, zv, zv};
    #pragma unroll
    for (int kt = 0; kt < 4; ++kt){
      us8 ra;
      switch (kt){
        case 0: ra = huL; break;
        case 1: ra = huH; break;
        case 2: ra = hvL; break;
        default: ra = hvH; break;
      }
      bf16x8 a = __builtin_bit_cast(bf16x8, ra);
      #pragma unroll
      for (int nt = 0; nt < 4; ++nt)
        acc[nt] = __builtin_amdgcn_mfma_f32_16x16x32_bf16(a, Bh[kt][nt], acc[nt], 0, 0, 0);
    }
    #pragma unroll
    for (int kt = 4; kt < 8; ++kt){
      us8 ra;
      switch (kt){
        case 4: ra = dL; break;
        case 5: ra = dH; break;
        case 6: ra = mL; break;
        default: ra = mH; break;
      }
      bf16x8 a = __builtin_bit_cast(bf16x8, ra);
      int kb = kt*32 + g*8;
      #pragma unroll
      for (int nt = 0; nt < 4; ++nt){
        bf16x8 b = *(bf16x8*)&Bt[swzi<512>(nt*16 + r16, kb*2)];
        acc[nt] = __builtin_amdgcn_mfma_f32_16x16x32_bf16(a, b, acc[nt], 0, 0, 0);
      }
    }
    float p0 = 0.f, p1 = 0.f, p2 = 0.f, p3 = 0.f;
    #pragma unroll
    for (int nt = 0; nt < 4; ++nt){
      float bb = be1v[nt], w2 = we2v[nt];
      p0 += fmaxf(acc[nt][0] + bb, 0.f) * w2;
      p1 += fmaxf(acc[nt][1] + bb, 0.f) * w2;
      p2 += fmaxf(acc[nt][2] + bb, 0.f) * w2;
      p3 += fmaxf(acc[nt][3] + bb, 0.f) * w2;
    }
    #pragma unroll
    for (int m = 1; m < 16; m <<= 1){
      p0 += __shfl_xor(p0, m);
      p1 += __shfl_xor(p1, m);
      p2 += __shfl_xor(p2, m);
      p3 += __shfl_xor(p3, m);
    }
    if (r16 == 0){
      int eb = tile*64 + w*16 + g*4;
      out[eb+0] = p0 + be2v;
      out[eb+1] = p1 + be2v;
      out[eb+2] = p2 + be2v;
      out[eb+3] = p3 + be2v;
    }
    __syncthreads();
  }
}

extern "C" void kernel_launch(void* const* d_in, const int* in_sizes, int n_in,
                              void* d_out, int out_size, void* d_ws, size_t ws_size,
                              hipStream_t stream){
  (void)in_sizes; (void)n_in; (void)out_size; (void)ws_size;
  const float* x       = (const float*)d_in[0];
  const int*   pos_row = (const int*)d_in[1];
  const int*   pos_col = (const int*)d_in[2];
  const float* pos_val = (const float*)d_in[3];
  const int*   neg_row = (const int*)d_in[4];
  const int*   neg_col = (const int*)d_in[5];
  const float* neg_val = (const float*)d_in[6];
  const int*   ei      = (const int*)d_in[7];
  const float* Wi      = (const float*)d_in[8];
  const float* bi      = (const float*)d_in[9];
  const float* Wg      = (const float*)d_in[10];
  const float* bg      = (const float*)d_in[11];
  const float* Wo      = (const float*)d_in[12];
  const float* bo      = (const float*)d_in[13];
  const float* We1     = (const float*)d_in[14];
  const float* be1     = (const float*)d_in[15];
  const float* We2     = (const float*)d_in[16];
  const float* be2     = (const float*)d_in[17];
  float* out = (float*)d_out;

  char* ws = (char*)d_ws;
  size_t off = 0;
  auto alloc = [&](size_t b)->char*{
    char* p = ws + off; off = (off + b + 255) & ~(size_t)255; return p;
  };
  unsigned short* hb  = (unsigned short*)alloc((size_t)NN*64*2);
  unsigned short* hpb = (unsigned short*)alloc((size_t)NN*64*2);
  unsigned short* hnb = (unsigned short*)alloc((size_t)NN*64*2);
  int2*  tmpP = (int2*)alloc((size_t)NNZV*8);
  int2*  tmpN = (int2*)alloc((size_t)NNZV*8);
  int2*  csvP = (int2*)alloc((size_t)NNZV*8);
  int2*  csvN = (int2*)alloc((size_t)NNZV*8);
  int*   rpP  = (int*)alloc((size_t)(NN+1)*4);
  int*   rpN  = (int*)alloc((size_t)(NN+1)*4);
  int*   gh   = (int*)alloc((size_t)2*NCH*NB*4);
  int*   tot  = (int*)alloc((size_t)2*NB*4);
  int*   bbase= (int*)alloc((size_t)2*(NB+1)*4);

  hipMemsetAsync(tot, 0, (size_t)2*NB*4, stream);
  k_bhist<<<2*NCH, 256, 0, stream>>>(pos_row, neg_row, gh, tot);
  k_boff<<<(2*NB+3)/4, 256, 0, stream>>>(tot, bbase, gh);
  k_psort<<<2*NCH, 256, 0, stream>>>(pos_row, pos_col, pos_val,
                                     neg_row, neg_col, neg_val,
                                     gh, tmpP, tmpN);
  k_rsini<<<2*NB + (NN+63)/64, 256, 0, stream>>>(bbase, tmpP, tmpN,
      csvP, csvN, rpP, rpN, x, Wi, bi, hb);
  for (int hop = 0; hop < 2; ++hop){
    k_spmm<<<(2*NN+3)/4, 256, 0, stream>>>(rpP, csvP, rpN, csvN, hb, hpb, hnb);
    k_gate<<<(NN+63)/64, 256, 0, stream>>>(hpb, hnb,
        Wg + (size_t)hop*128*64, bg + (size_t)hop*64,
        Wo + (size_t)hop*64*64,  bo + (size_t)hop*64, hb);
  }
  k_edge<<<2048, 256, 0, stream>>>(ei, hb, We1, be1, We2, be2, out);
}